// Round 3
// baseline (60.713 us; speedup 1.0000x reference)
//
#include <hip/hip_runtime.h>

// PatchManifoldLossPre: resize (8,19,512,512) -> (8,19,48,48) with jax.image.resize
// bilinear (antialias=True, triangle kernel, half-pixel centers), split into 4x4
// patches of 12x12, P[16, 21888], value = mean(weights * pairwise-MSD(P)).
// pairwise-MSD via Gram: map[a,b] = (G[aa]+G[bb]-2G[ab])/N.
//
// Round-3 structure: 2 dispatches total.
//  k_resize     — vertical-first resize (coalesced global float4 reads, no LDS for
//                 the vertical pass), horizontal gather from a swizzled LDS tile
//                 (c -> c + 4*(c>>5), row stride 580, ~2-way conflicts = free).
//                 Block 0 also zeroes G + ticket (replaces the memset dispatch).
//                 H and V resize use ONE shared 48-entry weight table (identical).
//  k_gram_final — per-bc Gram into G via atomics, then last-block (device ticket)
//                 computes the weighted scalar. Coherent G readback via atomic read.

#define HIN 512
#define WOUT 48
#define NTAP 22
#define NBC 152          // 8*19
#define GRP 6            // output rows per resize block
#define NGRP 8
#define TSTRIDE 580      // padded LDS row stride in floats
#define GROUP 12         // patch size
#define KS (512.0 / 48.0)

// Triangle-kernel resize weights matching jax.image.resize(method="bilinear",
// antialias=True): sample s=(i+0.5)*KS-0.5, kernel scale KS, normalize over valid
// taps. Window clamped into [0, HIN-NTAP]; clamped-in taps all have zero weight.
__device__ __forceinline__ int compute_weights(int i, float* w) {
  double s = (i + 0.5) * KS - 0.5;
  int stc = (int)ceil(s - KS);
  if (stc < 0) stc = 0;
  if (stc > HIN - NTAP) stc = HIN - NTAP;
  double wr[NTAP];
  double sum = 0.0;
#pragma unroll
  for (int k = 0; k < NTAP; ++k) {
    int j = stc + k;
    double d = fabs(s - (double)j) * (1.0 / KS);
    double wv = 1.0 - d;
    if (wv < 0.0) wv = 0.0;
    if (j >= HIN) wv = 0.0;  // j<0 impossible after clamp
    wr[k] = wv;
    sum += wv;
  }
  double inv = 1.0 / sum;
#pragma unroll
  for (int k = 0; k < NTAP; ++k) w[k] = (float)(wr[k] * inv);
  return stc;
}

__global__ __launch_bounds__(256, 4) void k_resize(const float* __restrict__ pred,
                                                   float* __restrict__ smallimg,
                                                   float* __restrict__ G,
                                                   unsigned* __restrict__ ticket) {
  __shared__ float tile[GRP * TSTRIDE];  // 13920 B, swizzled rows
  __shared__ float hw[NTAP][WOUT];       // 4224 B (shared by H and V passes)
  __shared__ int hst[WOUT];

  const int t = threadIdx.x;
  const int bc = blockIdx.x >> 3;
  const int oy0 = (blockIdx.x & 7) * GRP;

  // Replace the memset dispatch: block 0 initializes G + ticket (plain stores,
  // visible to k_gram_final at the kernel boundary on the same stream).
  if (blockIdx.x == 0) {
    G[t] = 0.f;
    if (t == 0) *ticket = 0u;
  }

  if (t < WOUT) {
    float wreg[NTAP];
    hst[t] = compute_weights(t, wreg);
#pragma unroll
    for (int k = 0; k < NTAP; ++k) hw[k][t] = wreg[k];
  }
  __syncthreads();

  // Vertical pass: each thread owns one float4 column slice for 3 output rows.
  // Global reads are 1KB-contiguous per wave; adjacent windows overlap ~11 of 22
  // rows -> L1 reuse. Weight reads hw[k][oy0+r] are wave-uniform -> broadcast.
  const float* img = pred + (size_t)bc * (HIN * HIN);
  const int slot = t >> 7;        // 0..1
  const int x = (t & 127) << 2;   // 0..508
  const int xph = x + ((x >> 5) << 2);
#pragma unroll
  for (int i = 0; i < 3; ++i) {
    const int r = slot * 3 + i;
    const int base = hst[oy0 + r];
    float4 a = make_float4(0.f, 0.f, 0.f, 0.f);
#pragma unroll
    for (int k = 0; k < NTAP; ++k) {
      const float4 v =
          *reinterpret_cast<const float4*>(img + (size_t)(base + k) * HIN + x);
      const float wk = hw[k][oy0 + r];
      a.x = fmaf(wk, v.x, a.x);
      a.y = fmaf(wk, v.y, a.y);
      a.z = fmaf(wk, v.z, a.z);
      a.w = fmaf(wk, v.w, a.w);
    }
    *reinterpret_cast<float4*>(&tile[r * TSTRIDE + xph]) = a;
  }
  __syncthreads();

  // Horizontal gather from swizzled tile -> smallimg (coalesced stores).
  for (int it = 0; it < 2; ++it) {
    const int item = it * 256 + t;
    if (item >= GRP * WOUT) break;
    const int r = item / WOUT;
    const int j = item - r * WOUT;
    const int stc = hst[j];
    const int rb = r * TSTRIDE;
    float acc = 0.f;
#pragma unroll
    for (int k = 0; k < NTAP; ++k) {
      const int cc = stc + k;
      acc = fmaf(hw[k][j], tile[rb + cc + ((cc >> 5) << 2)], acc);
    }
    smallimg[(size_t)bc * (WOUT * WOUT) + (oy0 + r) * WOUT + j] = acc;
  }
}

// One block per (b,c): stage 48x48 image in LDS, thread owns pair (a,b), Gram via
// atomics into G; the LAST block (device-scope ticket) computes the final scalar.
__global__ __launch_bounds__(256) void k_gram_final(const float* __restrict__ smallimg,
                                                    const float* __restrict__ wts,
                                                    float* __restrict__ G,
                                                    unsigned* __restrict__ ticket,
                                                    float* __restrict__ out) {
  __shared__ float img[WOUT * WOUT];
  __shared__ float Gs[256];
  __shared__ float partial[4];
  __shared__ unsigned lastv;

  const int tid = threadIdx.x;
  const float* src = smallimg + (size_t)blockIdx.x * (WOUT * WOUT);
  for (int idx = tid; idx < (WOUT * WOUT) / 4; idx += 256) {
    *reinterpret_cast<float4*>(&img[idx * 4]) =
        *reinterpret_cast<const float4*>(src + idx * 4);
  }
  __syncthreads();
  const int a = tid >> 4;
  const int b = tid & 15;
  const float* pa = &img[((a >> 2) * GROUP) * WOUT + (a & 3) * GROUP];
  const float* pb = &img[((b >> 2) * GROUP) * WOUT + (b & 3) * GROUP];
  float acc = 0.f;
  for (int y = 0; y < GROUP; ++y) {
#pragma unroll
    for (int x = 0; x < GROUP; ++x) {
      acc += pa[y * WOUT + x] * pb[y * WOUT + x];
    }
  }
  atomicAdd(&G[tid], acc);
  __threadfence();   // release: G-atomics ordered before the ticket increment
  __syncthreads();   // all 256 lanes' atomics issued+fenced before tid 0 tickets
  if (tid == 0) lastv = atomicAdd(ticket, 1u);
  __syncthreads();
  if (lastv != NBC - 1) return;

  // Last block: coherent readback of G (device-scope atomic read), then reduce.
  __threadfence();
  Gs[tid] = atomicAdd(&G[tid], 0.f);
  __syncthreads();
  float v = wts[tid] * (Gs[a * 17] + Gs[b * 17] - 2.0f * Gs[tid]);
#pragma unroll
  for (int off = 32; off > 0; off >>= 1) v += __shfl_down(v, off, 64);
  if ((tid & 63) == 0) partial[tid >> 6] = v;
  __syncthreads();
  if (tid == 0) {
    out[0] = (partial[0] + partial[1] + partial[2] + partial[3]) *
             (float)(1.0 / (256.0 * 21888.0));
  }
}

extern "C" void kernel_launch(void* const* d_in, const int* in_sizes, int n_in,
                              void* d_out, int out_size, void* d_ws, size_t ws_size,
                              hipStream_t stream) {
  const float* pred = (const float*)d_in[0];
  const float* wts = (const float*)d_in[1];
  float* out = (float*)d_out;
  float* G = (float*)d_ws;                              // bytes [0, 1024)
  unsigned* ticket = (unsigned*)((char*)d_ws + 1024);   // bytes [1024, 1028)
  float* smallimg = (float*)((char*)d_ws + 2048);       // 152*48*48 floats

  hipLaunchKernelGGL(k_resize, dim3(NBC * NGRP), dim3(256), 0, stream,
                     pred, smallimg, G, ticket);
  hipLaunchKernelGGL(k_gram_final, dim3(NBC), dim3(256), 0, stream,
                     smallimg, wts, G, ticket, out);
}